// Round 1
// baseline (233.806 us; speedup 1.0000x reference)
//
#include <hip/hip_runtime.h>
#include <hip/hip_bf16.h>

typedef __bf16 bf16_t;
typedef __bf16 bf16x8 __attribute__((ext_vector_type(8)));
typedef __bf16 bf16x4 __attribute__((ext_vector_type(4)));
typedef float  f32x4  __attribute__((ext_vector_type(4)));

#define SEQ    2048
#define BATCH  2
#define NHEAD  16
#define HDIM   64
#define DMODEL 1024
#define WIN    256

// ---------------------------------------------------------------------------
// Kernel 1: cast x (fp32) -> bf16, flat [4096][1024]
// ---------------------------------------------------------------------------
__global__ void cast_x_kernel(const float* __restrict__ x, bf16_t* __restrict__ xb, int n4) {
    int i = blockIdx.x * blockDim.x + threadIdx.x;
    if (i >= n4) return;
    float4 v = ((const float4*)x)[i];
    bf16x4 o;
    o[0] = (bf16_t)v.x; o[1] = (bf16_t)v.y; o[2] = (bf16_t)v.z; o[3] = (bf16_t)v.w;
    ((bf16x4*)xb)[i] = o;
}

// ---------------------------------------------------------------------------
// Kernel 2: transpose+cast the 4 weight matrices into Wt[4][1024][1024],
// Wt[sel][n][k] = W_sel[k][n]  (B^T layout so GEMM B-fragments are contiguous)
// ---------------------------------------------------------------------------
__global__ void transpose_w_kernel(const float* __restrict__ Wq, const float* __restrict__ Wk,
                                   const float* __restrict__ Wv, const float* __restrict__ Wo,
                                   bf16_t* __restrict__ Wt) {
    __shared__ float tile[32][33];
    const float* W = (blockIdx.z == 0) ? Wq : (blockIdx.z == 1) ? Wk : (blockIdx.z == 2) ? Wv : Wo;
    bf16_t* out = Wt + (size_t)blockIdx.z * DMODEL * DMODEL;
    int k0 = blockIdx.y * 32, n0 = blockIdx.x * 32;
    int tx = threadIdx.x, ty = threadIdx.y;  // block (32, 8)
#pragma unroll
    for (int i = 0; i < 4; i++)
        tile[ty + i * 8][tx] = W[(size_t)(k0 + ty + i * 8) * DMODEL + n0 + tx];
    __syncthreads();
#pragma unroll
    for (int i = 0; i < 4; i++)
        out[(size_t)(n0 + ty + i * 8) * DMODEL + k0 + tx] = (bf16_t)tile[tx][ty + i * 8];
}

// ---------------------------------------------------------------------------
// GEMM: C[M][N] = A[M][K] * Bt[N][K]^T, 128x128 block tile, 256 thr = 4 waves,
// each wave a 64x64 subtile = 4x4 grid of 16x16x32 bf16 MFMAs.
// EPI 0: QKV scatter epilogue (Q scaled 0.125; K [B,H,S,64]; V^T [B,H,64,S])
// EPI 1: Out[mg][ng] = acc + bo[ng]  (fp32)
// ---------------------------------------------------------------------------
template <int EPI>
__global__ __launch_bounds__(256) void gemm_bt_kernel(
    const bf16_t* __restrict__ A, const bf16_t* __restrict__ Bt,
    bf16_t* __restrict__ Qb, bf16_t* __restrict__ Kb, bf16_t* __restrict__ Vt,
    float* __restrict__ Out, const float* __restrict__ bo, int K) {
    __shared__ __attribute__((aligned(16))) bf16_t As[128][72];
    __shared__ __attribute__((aligned(16))) bf16_t Bs[128][72];
    const int tid = threadIdx.x;
    const int wave = tid >> 6, lane = tid & 63, quad = lane >> 4, l15 = lane & 15;
    const int wm = wave >> 1, wn = wave & 1;
    const int m0 = blockIdx.y * 128, n0 = blockIdx.x * 128;

    f32x4 acc[4][4] = {};

    for (int kt = 0; kt < K; kt += 64) {
#pragma unroll
        for (int i = 0; i < 4; i++) {
            int v = tid + i * 256;
            int row = v >> 3, c8 = (v & 7) * 8;
            *(bf16x8*)&As[row][c8] = *(const bf16x8*)(A + (size_t)(m0 + row) * K + kt + c8);
            *(bf16x8*)&Bs[row][c8] = *(const bf16x8*)(Bt + (size_t)(n0 + row) * K + kt + c8);
        }
        __syncthreads();
#pragma unroll
        for (int kk = 0; kk < 64; kk += 32) {
            bf16x8 am[4], bn[4];
#pragma unroll
            for (int i = 0; i < 4; i++)
                am[i] = *(const bf16x8*)&As[wm * 64 + i * 16 + l15][kk + quad * 8];
#pragma unroll
            for (int j = 0; j < 4; j++)
                bn[j] = *(const bf16x8*)&Bs[wn * 64 + j * 16 + l15][kk + quad * 8];
#pragma unroll
            for (int i = 0; i < 4; i++)
#pragma unroll
                for (int j = 0; j < 4; j++)
                    acc[i][j] = __builtin_amdgcn_mfma_f32_16x16x32_bf16(am[i], bn[j], acc[i][j], 0, 0, 0);
        }
        __syncthreads();
    }

#pragma unroll
    for (int i = 0; i < 4; i++)
#pragma unroll
        for (int j = 0; j < 4; j++)
#pragma unroll
            for (int r = 0; r < 4; r++) {
                int mg = m0 + wm * 64 + i * 16 + quad * 4 + r;
                int ng = n0 + wn * 64 + j * 16 + l15;
                float v = acc[i][j][r];
                if (EPI == 0) {
                    int sel = ng >> 10, nl = ng & 1023, h = nl >> 6, d = nl & 63;
                    int b = mg >> 11, s = mg & 2047;
                    size_t idx = ((size_t)((b * NHEAD + h) * SEQ) + s) * HDIM + d;
                    if (sel == 0)      Qb[idx] = (bf16_t)(v * 0.125f);
                    else if (sel == 1) Kb[idx] = (bf16_t)v;
                    else               Vt[((size_t)((b * NHEAD + h) * HDIM) + d) * SEQ + s] = (bf16_t)v;
                } else {
                    Out[(size_t)mg * DMODEL + ng] = v + bo[ng];
                }
            }
}

// ---------------------------------------------------------------------------
// Attention: one block (256 thr = 4 waves) per (b, h, 64-query tile).
// Window 256 is tile-aligned: key tiles q0/64 - 4 .. q0/64 + 4 (clamped).
// Wave w owns queries [q0+16w, q0+16w+16). Online softmax, O accum in regs.
// ---------------------------------------------------------------------------
__global__ __launch_bounds__(256) void attn_kernel(
    const bf16_t* __restrict__ Qb, const bf16_t* __restrict__ Kb,
    const bf16_t* __restrict__ Vt, bf16_t* __restrict__ ctx) {
    __shared__ __attribute__((aligned(16))) bf16_t Plds[4][16][72];
    const int tid = threadIdx.x;
    const int wave = tid >> 6, lane = tid & 63, quad = lane >> 4, l15 = lane & 15;
    const int b = blockIdx.z, h = blockIdx.y, q0 = blockIdx.x * 64;
    const int qbase = q0 + wave * 16;

    const bf16_t* Qp = Qb + (size_t)(b * NHEAD + h) * SEQ * HDIM;
    const bf16_t* Kp = Kb + (size_t)(b * NHEAD + h) * SEQ * HDIM;
    const bf16_t* Vp = Vt + (size_t)(b * NHEAD + h) * HDIM * SEQ;

    // Q A-fragments: lane holds Q[qbase + l15][quad*8 .. +8] (two 32-wide k chunks)
    bf16x8 qa0 = *(const bf16x8*)(Qp + (size_t)(qbase + l15) * HDIM + quad * 8);
    bf16x8 qa1 = *(const bf16x8*)(Qp + (size_t)(qbase + l15) * HDIM + 32 + quad * 8);

    f32x4 O[4] = {};
    float m_r[4], l_r[4];
#pragma unroll
    for (int r = 0; r < 4; r++) { m_r[r] = -1e30f; l_r[r] = 0.f; }

    const int qt = q0 >> 6;
    const int t0 = (qt - 4 > 0) ? qt - 4 : 0;
    const int t1 = (qt + 4 < SEQ / 64 - 1) ? qt + 4 : SEQ / 64 - 1;

    for (int kt = t0; kt <= t1; kt++) {
        const int k0 = kt * 64;
        f32x4 s[4];
#pragma unroll
        for (int c = 0; c < 4; c++) {
            const bf16_t* kr = Kp + (size_t)(k0 + c * 16 + l15) * HDIM;
            bf16x8 kb0 = *(const bf16x8*)(kr + quad * 8);
            bf16x8 kb1 = *(const bf16x8*)(kr + 32 + quad * 8);
            f32x4 a = {};
            a = __builtin_amdgcn_mfma_f32_16x16x32_bf16(qa0, kb0, a, 0, 0, 0);
            a = __builtin_amdgcn_mfma_f32_16x16x32_bf16(qa1, kb1, a, 0, 0, 0);
            s[c] = a;
        }
        // band mask — only edge tiles (|dt| == 4) can have out-of-window pairs
        int dt = kt - qt;
        if (dt <= -4 || dt >= 4) {
#pragma unroll
            for (int c = 0; c < 4; c++)
#pragma unroll
                for (int r = 0; r < 4; r++) {
                    int i = qbase + quad * 4 + r;
                    int j = k0 + c * 16 + l15;
                    int dd = i - j; dd = (dd < 0) ? -dd : dd;
                    if (dd > WIN) s[c][r] = -1e30f;
                }
        }
        // online softmax per row (row r lives in 16 lanes of this quad)
#pragma unroll
        for (int r = 0; r < 4; r++) {
            float mt = fmaxf(fmaxf(s[0][r], s[1][r]), fmaxf(s[2][r], s[3][r]));
#pragma unroll
            for (int m = 1; m < 16; m <<= 1) mt = fmaxf(mt, __shfl_xor(mt, m));
            float mn = fmaxf(m_r[r], mt);
            float alpha = __expf(m_r[r] - mn);
            float lsum = 0.f;
#pragma unroll
            for (int c = 0; c < 4; c++) {
                float p = __expf(s[c][r] - mn);
                s[c][r] = p;
                lsum += p;
            }
#pragma unroll
            for (int m = 1; m < 16; m <<= 1) lsum += __shfl_xor(lsum, m);
            l_r[r] = l_r[r] * alpha + lsum;
            m_r[r] = mn;
#pragma unroll
            for (int d = 0; d < 4; d++) O[d][r] *= alpha;
        }
        // P: C/D layout -> A layout via this wave's private LDS strip
#pragma unroll
        for (int c = 0; c < 4; c++)
#pragma unroll
            for (int r = 0; r < 4; r++)
                Plds[wave][quad * 4 + r][c * 16 + l15] = (bf16_t)s[c][r];
        bf16x8 pa0 = *(const bf16x8*)&Plds[wave][l15][quad * 8];
        bf16x8 pa1 = *(const bf16x8*)&Plds[wave][l15][32 + quad * 8];
#pragma unroll
        for (int d = 0; d < 4; d++) {
            const bf16_t* vr = Vp + (size_t)(d * 16 + l15) * SEQ + k0;
            bf16x8 vb0 = *(const bf16x8*)(vr + quad * 8);
            bf16x8 vb1 = *(const bf16x8*)(vr + 32 + quad * 8);
            O[d] = __builtin_amdgcn_mfma_f32_16x16x32_bf16(pa0, vb0, O[d], 0, 0, 0);
            O[d] = __builtin_amdgcn_mfma_f32_16x16x32_bf16(pa1, vb1, O[d], 0, 0, 0);
        }
    }

#pragma unroll
    for (int r = 0; r < 4; r++) {
        float inv = 1.0f / l_r[r];
        int i = qbase + quad * 4 + r;
#pragma unroll
        for (int d = 0; d < 4; d++) {
            float v = O[d][r] * inv;
            ctx[((size_t)(b * SEQ + i)) * DMODEL + h * HDIM + d * 16 + l15] = (bf16_t)v;
        }
    }
}

// ---------------------------------------------------------------------------
extern "C" void kernel_launch(void* const* d_in, const int* in_sizes, int n_in,
                              void* d_out, int out_size, void* d_ws, size_t ws_size,
                              hipStream_t stream) {
    const float* x  = (const float*)d_in[0];
    const float* Wq = (const float*)d_in[1];
    const float* Wk = (const float*)d_in[2];
    const float* Wv = (const float*)d_in[3];
    const float* Wo = (const float*)d_in[4];
    const float* bo = (const float*)d_in[5];
    float* out = (float*)d_out;

    const size_t MTOK = (size_t)BATCH * SEQ;          // 4096
    bf16_t* xb  = (bf16_t*)d_ws;                      // 4096*1024
    bf16_t* Wt  = xb + MTOK * DMODEL;                 // 4*1024*1024 (q,k,v,o transposed)
    bf16_t* Qb  = Wt + (size_t)4 * DMODEL * DMODEL;   // [B,H,S,64]
    bf16_t* Kb  = Qb + MTOK * DMODEL;                 // [B,H,S,64]
    bf16_t* Vt  = Kb + MTOK * DMODEL;                 // [B,H,64,S]
    bf16_t* ctx = Vt + MTOK * DMODEL;                 // [4096][1024]

    cast_x_kernel<<<dim3((MTOK * DMODEL / 4 + 255) / 256), dim3(256), 0, stream>>>(
        x, xb, (int)(MTOK * DMODEL / 4));
    transpose_w_kernel<<<dim3(32, 32, 4), dim3(32, 8), 0, stream>>>(Wq, Wk, Wv, Wo, Wt);
    // QKV: M=4096, N=3072, K=1024
    gemm_bt_kernel<0><<<dim3(24, 32), dim3(256), 0, stream>>>(
        xb, Wt, Qb, Kb, Vt, nullptr, nullptr, DMODEL);
    attn_kernel<<<dim3(SEQ / 64, NHEAD, BATCH), dim3(256), 0, stream>>>(Qb, Kb, Vt, ctx);
    // Out: M=4096, N=1024, K=1024
    gemm_bt_kernel<1><<<dim3(8, 32), dim3(256), 0, stream>>>(
        ctx, Wt + (size_t)3 * DMODEL * DMODEL, nullptr, nullptr, nullptr, out, bo, DMODEL);
}